// Round 16
// baseline (1350.572 us; speedup 1.0000x reference)
//
#include <hip/hip_runtime.h>

#define NNODES 50000
#define HDIM 256
#define NLAYERS 4
#define NEDGES 800000
#define FIN 1280
#define LDOUT 1024

typedef _Float16 f16;
typedef __attribute__((ext_vector_type(8))) _Float16 f16x8;
typedef __attribute__((ext_vector_type(4))) _Float16 f16x4;
typedef __attribute__((ext_vector_type(4))) float f32x4;

// ---------------------------------------------------------------------------
// MFMA layouts refcheck-validated R3-R15: A row=l&15, k=(l>>4)*8+j (+32kb);
// B col=l&15 (col-major Wt); C/D col=l&15, row=(l>>4)*4+reg.
// Frag-major LDS tile (64 rows x 64 k, 8 KB): region r=(kb*4+rf) holds 64
// lane-slots of 16 B; read: &Asm[((kb*4+rf)*64+l)*8].
// global_load_lds staging (this round): wave-uniform LDS dest (base+lane*16),
// per-lane global src -> region r's src = A[row0+ (r&3)*16+(l&15)]
// [kt*64+(r>>2)*32+(l>>4)*8].  Write pattern == verified read pattern.
// R14 lesson kept: A staged through LDS (coalesced + block reuse).
// ---------------------------------------------------------------------------

__device__ __forceinline__ void gll16(const f16* g, f16* l)
{
    __builtin_amdgcn_global_load_lds(
        (const __attribute__((address_space(1))) void*)g,
        (__attribute__((address_space(3))) void*)l,
        16, 0, 0);
}

// ---------------------------------------------------------------------------
// esm f32 -> f16 (one-shot stream)
// ---------------------------------------------------------------------------
__global__ __launch_bounds__(256) void tof16_k(
    const float* __restrict__ in, f16* __restrict__ out)
{
    const long nq = (long)NNODES * FIN / 4;          // 16M float4 groups
    for (long i = (long)blockIdx.x * 256 + threadIdx.x; i < nq;
         i += (long)gridDim.x * 256) {
        const float4 v = ((const float4*)in)[i];
        f16x4 r;
        r[0] = (f16)v.x; r[1] = (f16)v.y; r[2] = (f16)v.z; r[3] = (f16)v.w;
        ((f16x4*)out)[i] = r;
    }
}

// ---------------------------------------------------------------------------
// lin0: xh = f16(esmh @ lin0t + b)   K=1280, gll staging, 1 barrier/tile
// ---------------------------------------------------------------------------
__global__ __launch_bounds__(256) void lin0h_k(
    const f16*  __restrict__ esmh,     // [N][1280] f16
    const f16*  __restrict__ Wt,       // [256 cols][1280] col-major f16
    const float* __restrict__ bias,
    f16* __restrict__ xh)
{
    constexpr int KTILES = FIN / 64;   // 20
    __shared__ f16 Asm[2][4096];       // 2 x 8 KB

    const int row0 = blockIdx.x * 64;
    const int tid = threadIdx.x;
    const int wv = tid >> 6;
    const int l = tid & 63;

    const f16* bp[4];
    #pragma unroll
    for (int cf = 0; cf < 4; ++cf)
        bp[cf] = Wt + (size_t)(wv * 64 + cf * 16 + (l & 15)) * FIN + ((l >> 4) * 8);

    f32x4 acc[4][4] = {};

    auto STAGE = [&](int b, int kt) {
        #pragma unroll
        for (int i = 0; i < 2; ++i) {
            const int r = wv * 2 + i;
            const int rf = r & 3, kb = r >> 2;
            int gr = row0 + rf * 16 + (l & 15);
            gr = (gr < NNODES) ? gr : (NNODES - 1);
            gll16(esmh + (size_t)gr * FIN + kt * 64 + kb * 32 + ((l >> 4) * 8),
                  &Asm[b][r * 512]);
        }
    };

    STAGE(0, 0);
    int cur = 0;
    #pragma unroll
    for (int kt = 0; kt < KTILES; ++kt) {
        __syncthreads();                       // buf[cur] staged (vmcnt drained)
        if (kt + 1 < KTILES) STAGE(cur ^ 1, kt + 1);   // in flight over compute
        f16x8 af[4][2];
        #pragma unroll
        for (int rf = 0; rf < 4; ++rf)
            #pragma unroll
            for (int kb = 0; kb < 2; ++kb)
                af[rf][kb] = *(const f16x8*)(&Asm[cur][((kb * 4 + rf) * 64 + l) * 8]);
        f16x8 bf[4][2];
        #pragma unroll
        for (int cf = 0; cf < 4; ++cf) {
            bf[cf][0] = *(const f16x8*)(bp[cf] + kt * 64);
            bf[cf][1] = *(const f16x8*)(bp[cf] + kt * 64 + 32);
        }
        #pragma unroll
        for (int cf = 0; cf < 4; ++cf)
            #pragma unroll
            for (int rf = 0; rf < 4; ++rf)
                #pragma unroll
                for (int kb = 0; kb < 2; ++kb)
                    acc[rf][cf] = __builtin_amdgcn_mfma_f32_16x16x32_f16(
                        af[rf][kb], bf[cf][kb], acc[rf][cf], 0, 0, 0);
        cur ^= 1;
    }

    #pragma unroll
    for (int rf = 0; rf < 4; ++rf) {
        #pragma unroll
        for (int j = 0; j < 4; ++j) {
            const int row = row0 + rf * 16 + ((l >> 4) * 4) + j;
            if (row >= NNODES) continue;
            #pragma unroll
            for (int cf = 0; cf < 4; ++cf) {
                const int col = wv * 64 + cf * 16 + (l & 15);
                xh[(size_t)row * HDIM + col] = (f16)(acc[rf][cf][j] + bias[col]);
            }
        }
    }
}

// ---------------------------------------------------------------------------
// Fused h + mask GEMM (hm_k), gll staging:
// phase A: h = relu([aggx|xm]@[W2;W1] + deg*b2 + b1)  (K=512) -> frag LDS
// phase B: mask = sigmoid(h@W3 + b3); epilogue: maskh=m, xg=xh*m
// ---------------------------------------------------------------------------
__global__ __launch_bounds__(256) void hm_k(
    const f16*  __restrict__ aggx,
    const f16*  __restrict__ xm,
    const f16*  __restrict__ xh,
    const int*  __restrict__ deg,
    const f16*  __restrict__ WH,      // [256][512] col-major
    const f16*  __restrict__ W3t,     // [256][256] col-major
    const float* __restrict__ b2,
    const float* __restrict__ b1,
    const float* __restrict__ b3,
    f16* __restrict__ maskh,
    f16* __restrict__ xg)
{
    __shared__ f16 lds[16384];        // 32 KB: Asm dbuf overlay [0..8192) + Hfr
    f16 (*Asm)[4096] = (f16(*)[4096])lds;

    const int row0 = blockIdx.x * 64;
    const int tid = threadIdx.x;
    const int wv = tid >> 6;
    const int l = tid & 63;

    const f16* bp[4];
    #pragma unroll
    for (int cf = 0; cf < 4; ++cf)
        bp[cf] = WH + (size_t)(wv * 64 + cf * 16 + (l & 15)) * 512 + ((l >> 4) * 8);

    f32x4 acc[4][4] = {};

    auto STAGE = [&](int b, int kt) {
        const f16* base = (kt < 4) ? aggx : xm;
        const int ko = (kt & 3) * 64;
        #pragma unroll
        for (int i = 0; i < 2; ++i) {
            const int r = wv * 2 + i;
            const int rf = r & 3, kb = r >> 2;
            int gr = row0 + rf * 16 + (l & 15);
            gr = (gr < NNODES) ? gr : (NNODES - 1);
            gll16(base + (size_t)gr * HDIM + ko + kb * 32 + ((l >> 4) * 8),
                  &Asm[b][r * 512]);
        }
    };

    STAGE(0, 0);
    int cur = 0;
    #pragma unroll
    for (int kt = 0; kt < 8; ++kt) {
        __syncthreads();
        if (kt + 1 < 8) STAGE(cur ^ 1, kt + 1);
        f16x8 af[4][2];
        #pragma unroll
        for (int rf = 0; rf < 4; ++rf)
            #pragma unroll
            for (int kb = 0; kb < 2; ++kb)
                af[rf][kb] = *(const f16x8*)(&Asm[cur][((kb * 4 + rf) * 64 + l) * 8]);
        f16x8 bf[4][2];
        #pragma unroll
        for (int cf = 0; cf < 4; ++cf) {
            bf[cf][0] = *(const f16x8*)(bp[cf] + kt * 64);
            bf[cf][1] = *(const f16x8*)(bp[cf] + kt * 64 + 32);
        }
        #pragma unroll
        for (int cf = 0; cf < 4; ++cf)
            #pragma unroll
            for (int rf = 0; rf < 4; ++rf)
                #pragma unroll
                for (int kb = 0; kb < 2; ++kb)
                    acc[rf][cf] = __builtin_amdgcn_mfma_f32_16x16x32_f16(
                        af[rf][kb], bf[cf][kb], acc[rf][cf], 0, 0, 0);
        cur ^= 1;
    }
    __syncthreads();                  // Asm reads done -> reuse whole LDS as Hfr

    // epilogue A: h -> frag-major LDS
    #pragma unroll
    for (int rf = 0; rf < 4; ++rf) {
        #pragma unroll
        for (int j = 0; j < 4; ++j) {
            const int rowl = rf * 16 + ((l >> 4) * 4) + j;
            const int row = row0 + rowl;
            const float dv = (row < NNODES) ? (float)deg[row] : 0.f;
            #pragma unroll
            for (int cf = 0; cf < 4; ++cf) {
                const int col = wv * 64 + cf * 16 + (l & 15);
                const float h = fmaxf(acc[rf][cf][j] + dv * b2[col] + b1[col], 0.f);
                const int idx =
                    (((col >> 6) * 8 + ((col >> 5) & 1) * 4 + (rowl >> 4)) * 64
                     + ((col >> 3) & 3) * 16 + (rowl & 15)) * 8 + (col & 7);
                lds[idx] = (f16)h;
            }
        }
    }
    __syncthreads();

    // phase B: mask GEMM (A = Hfr, K=256)
    const f16* bp3[4];
    #pragma unroll
    for (int cf = 0; cf < 4; ++cf)
        bp3[cf] = W3t + (size_t)(wv * 64 + cf * 16 + (l & 15)) * 256 + ((l >> 4) * 8);

    f32x4 acc2[4][4] = {};
    #pragma unroll
    for (int kt = 0; kt < 4; ++kt) {
        f16x8 af[4][2];
        #pragma unroll
        for (int rf = 0; rf < 4; ++rf)
            #pragma unroll
            for (int kb = 0; kb < 2; ++kb)
                af[rf][kb] = *(const f16x8*)(&lds[((kt * 8 + kb * 4 + rf) * 64 + l) * 8]);
        f16x8 bf[4][2];
        #pragma unroll
        for (int cf = 0; cf < 4; ++cf) {
            bf[cf][0] = *(const f16x8*)(bp3[cf] + kt * 64);
            bf[cf][1] = *(const f16x8*)(bp3[cf] + kt * 64 + 32);
        }
        #pragma unroll
        for (int cf = 0; cf < 4; ++cf)
            #pragma unroll
            for (int rf = 0; rf < 4; ++rf)
                #pragma unroll
                for (int kb = 0; kb < 2; ++kb)
                    acc2[rf][cf] = __builtin_amdgcn_mfma_f32_16x16x32_f16(
                        af[rf][kb], bf[cf][kb], acc2[rf][cf], 0, 0, 0);
    }

    // epilogue B: mask + xg
    #pragma unroll
    for (int rf = 0; rf < 4; ++rf) {
        #pragma unroll
        for (int j = 0; j < 4; ++j) {
            const int row = row0 + rf * 16 + ((l >> 4) * 4) + j;
            if (row >= NNODES) continue;
            #pragma unroll
            for (int cf = 0; cf < 4; ++cf) {
                const int col = wv * 64 + cf * 16 + (l & 15);
                const float m = 1.f / (1.f + expf(-(acc2[rf][cf][j] + b3[col])));
                maskh[(size_t)row * HDIM + col] = (f16)m;
                xg[(size_t)row * HDIM + col] =
                    (f16)((float)xh[(size_t)row * HDIM + col] * m);
            }
        }
    }
}

// ---------------------------------------------------------------------------
// CATH2 GEMM, gll staging: x' = relu([agg2|xh]@[Wn;Wr] + bn)
// -> out (f32 ld 1024), xh (in-place: all global xh reads drained by the
//    last loop barrier; rows are block-local), xm' = x'*mask
// ---------------------------------------------------------------------------
__global__ __launch_bounds__(256) void cath2_k(
    const f16*  __restrict__ agg2,
    const f16*  __restrict__ xh,
    const f16*  __restrict__ Mh,
    const f16*  __restrict__ Wt,      // [256][512] col-major
    const float* __restrict__ bias,
    float* __restrict__ Cf, int ldc,
    f16*  __restrict__ Ch,            // xh (in-place)
    f16*  __restrict__ Ch3)           // xm'
{
    __shared__ f16 Asm[2][4096];

    const int row0 = blockIdx.x * 64;
    const int tid = threadIdx.x;
    const int wv = tid >> 6;
    const int l = tid & 63;

    const f16* bp[4];
    #pragma unroll
    for (int cf = 0; cf < 4; ++cf)
        bp[cf] = Wt + (size_t)(wv * 64 + cf * 16 + (l & 15)) * 512 + ((l >> 4) * 8);

    f32x4 acc[4][4] = {};

    auto STAGE = [&](int b, int kt) {
        const f16* base = (kt < 4) ? agg2 : xh;
        const int ko = (kt & 3) * 64;
        #pragma unroll
        for (int i = 0; i < 2; ++i) {
            const int r = wv * 2 + i;
            const int rf = r & 3, kb = r >> 2;
            int gr = row0 + rf * 16 + (l & 15);
            gr = (gr < NNODES) ? gr : (NNODES - 1);
            gll16(base + (size_t)gr * HDIM + ko + kb * 32 + ((l >> 4) * 8),
                  &Asm[b][r * 512]);
        }
    };

    STAGE(0, 0);
    int cur = 0;
    #pragma unroll
    for (int kt = 0; kt < 8; ++kt) {
        __syncthreads();
        if (kt + 1 < 8) STAGE(cur ^ 1, kt + 1);
        f16x8 af[4][2];
        #pragma unroll
        for (int rf = 0; rf < 4; ++rf)
            #pragma unroll
            for (int kb = 0; kb < 2; ++kb)
                af[rf][kb] = *(const f16x8*)(&Asm[cur][((kb * 4 + rf) * 64 + l) * 8]);
        f16x8 bf[4][2];
        #pragma unroll
        for (int cf = 0; cf < 4; ++cf) {
            bf[cf][0] = *(const f16x8*)(bp[cf] + kt * 64);
            bf[cf][1] = *(const f16x8*)(bp[cf] + kt * 64 + 32);
        }
        #pragma unroll
        for (int cf = 0; cf < 4; ++cf)
            #pragma unroll
            for (int rf = 0; rf < 4; ++rf)
                #pragma unroll
                for (int kb = 0; kb < 2; ++kb)
                    acc[rf][cf] = __builtin_amdgcn_mfma_f32_16x16x32_f16(
                        af[rf][kb], bf[cf][kb], acc[rf][cf], 0, 0, 0);
        cur ^= 1;
    }

    #pragma unroll
    for (int rf = 0; rf < 4; ++rf) {
        #pragma unroll
        for (int j = 0; j < 4; ++j) {
            const int row = row0 + rf * 16 + ((l >> 4) * 4) + j;
            if (row >= NNODES) continue;
            #pragma unroll
            for (int cf = 0; cf < 4; ++cf) {
                const int col = wv * 64 + cf * 16 + (l & 15);
                const float r = fmaxf(acc[rf][cf][j] + bias[col], 0.f);
                Cf[(size_t)row * ldc + col] = r;
                Ch[(size_t)row * HDIM + col] = (f16)r;
                Ch3[(size_t)row * HDIM + col] =
                    (f16)(r * (float)Mh[(size_t)row * HDIM + col]);
            }
        }
    }
}

// ---------------------------------------------------------------------------
// ONE fused weight-pack kernel.
// dst (f16): [lin0t 256x1280 col-major = 327680][WH 4x(256x512) = 524288]
//            [W3t 4x65536 = 262144][WtC 4x131072 = 524288]
// ---------------------------------------------------------------------------
__global__ __launch_bounds__(256) void pack_all_k(
    const float* __restrict__ lin0_W,
    const float* __restrict__ W2, const float* __restrict__ W1,
    const float* __restrict__ W3,
    const float* __restrict__ Wn, const float* __restrict__ Wr,
    f16* __restrict__ dst)
{
    int idx = blockIdx.x * 256 + threadIdx.x;
    const int total = 327680 + 524288 + 262144 + 524288;
    if (idx >= total) return;
    f16* d = dst + idx;
    if (idx < 327680) {                       // lin0t col-major [256][1280]
        const int col = idx / 1280, k = idx % 1280;
        *d = (f16)lin0_W[(size_t)k * 256 + col];
        return;
    }
    idx -= 327680;
    if (idx < 524288) {                       // WH = [W2;W1]
        const int i = idx / 131072;
        int r = idx % 131072;
        const int col = r / 512, k = r % 512;
        *d = (f16)(k < 256 ? W2[(size_t)i * 65536 + k * 256 + col]
                           : W1[(size_t)i * 65536 + (k - 256) * 256 + col]);
        return;
    }
    idx -= 524288;
    if (idx < 262144) {                       // W3t
        const int i = idx / 65536;
        int r = idx % 65536;
        const int col = r / 256, k = r % 256;
        *d = (f16)W3[(size_t)i * 65536 + k * 256 + col];
        return;
    }
    idx -= 262144;                            // WtC = [Wn;Wr]
    const int i = idx / 131072; int r = idx % 131072;
    const int col = r / 512, k = r % 512;
    *d = (f16)(k < 256 ? Wn[(size_t)i * 65536 + k * 256 + col]
                       : Wr[(size_t)i * 65536 + (k - 256) * 256 + col]);
}

// ---------------------------------------------------------------------------
// CSR build: histogram -> 3-phase hierarchical scan (R15-verified) -> fill
// ---------------------------------------------------------------------------
__global__ __launch_bounds__(256) void count_k(
    const int* __restrict__ dstIdx, int* __restrict__ counts)
{
    const int e = blockIdx.x * 256 + threadIdx.x;
    if (e < NEDGES) atomicAdd(&counts[dstIdx[e]], 1);
}

__global__ __launch_bounds__(256) void scan1_k(
    const int* __restrict__ counts, int* __restrict__ starts,
    int* __restrict__ bsums)
{
    __shared__ int sm[256];
    const int i = blockIdx.x * 256 + threadIdx.x;
    const int v = (i < NNODES) ? counts[i] : 0;
    sm[threadIdx.x] = v;
    __syncthreads();
    #pragma unroll
    for (int ofs = 1; ofs < 256; ofs <<= 1) {
        const int t = (threadIdx.x >= ofs) ? sm[threadIdx.x - ofs] : 0;
        __syncthreads();
        sm[threadIdx.x] += t;
        __syncthreads();
    }
    if (i < NNODES) starts[i] = sm[threadIdx.x] - v;
    if (threadIdx.x == 255) bsums[blockIdx.x] = sm[255];
}

__global__ __launch_bounds__(256) void scan2_k(int* __restrict__ bsums, int nb)
{
    __shared__ int sm[256];
    const int v = (threadIdx.x < nb) ? bsums[threadIdx.x] : 0;
    sm[threadIdx.x] = v;
    __syncthreads();
    #pragma unroll
    for (int ofs = 1; ofs < 256; ofs <<= 1) {
        const int t = (threadIdx.x >= ofs) ? sm[threadIdx.x - ofs] : 0;
        __syncthreads();
        sm[threadIdx.x] += t;
        __syncthreads();
    }
    if (threadIdx.x < nb) bsums[threadIdx.x] = sm[threadIdx.x] - v;
}

__global__ __launch_bounds__(256) void scan3_k(
    const int* __restrict__ bsums, int* __restrict__ starts)
{
    const int i = blockIdx.x * 256 + threadIdx.x;
    if (i < NNODES) starts[i] += bsums[blockIdx.x];
    if (i == 0) starts[NNODES] = NEDGES;
}

__global__ __launch_bounds__(256) void fillcsr_k(
    const int* __restrict__ srcIdx, const int* __restrict__ dstIdx,
    int* __restrict__ cursor, int* __restrict__ csr)
{
    const int e = blockIdx.x * 256 + threadIdx.x;
    if (e >= NEDGES) return;
    const int d = dstIdx[e];
    const int p = atomicAdd(&cursor[d], 1);
    csr[p] = srcIdx[e];
}

// ---------------------------------------------------------------------------
// gather-sum (R10-verified): one wave per node, f16 rows, f32 accum, unroll-4
// ---------------------------------------------------------------------------
__global__ __launch_bounds__(256) void gather_g_k(
    const f16* __restrict__ rows, const int* __restrict__ csr,
    const int* __restrict__ starts, f16* __restrict__ outp)
{
    const int node = (blockIdx.x * 256 + threadIdx.x) >> 6;
    const int lane = threadIdx.x & 63;
    if (node >= NNODES) return;
    const int e0 = starts[node], e1 = starts[node + 1];
    float a0=0,a1=0,a2=0,a3=0, b0=0,b1=0,b2=0,b3=0;
    int e = e0;
    for (; e + 3 < e1; e += 4) {
        const int s0=csr[e], s1=csr[e+1], s2=csr[e+2], s3=csr[e+3];
        f16x4 v0 = *(const f16x4*)(rows + (size_t)s0 * HDIM + lane * 4);
        f16x4 v1 = *(const f16x4*)(rows + (size_t)s1 * HDIM + lane * 4);
        f16x4 v2 = *(const f16x4*)(rows + (size_t)s2 * HDIM + lane * 4);
        f16x4 v3 = *(const f16x4*)(rows + (size_t)s3 * HDIM + lane * 4);
        a0 += (float)v0[0] + (float)v2[0]; a1 += (float)v0[1] + (float)v2[1];
        a2 += (float)v0[2] + (float)v2[2]; a3 += (float)v0[3] + (float)v2[3];
        b0 += (float)v1[0] + (float)v3[0]; b1 += (float)v1[1] + (float)v3[1];
        b2 += (float)v1[2] + (float)v3[2]; b3 += (float)v1[3] + (float)v3[3];
    }
    for (; e < e1; ++e) {
        const int s0 = csr[e];
        f16x4 v0 = *(const f16x4*)(rows + (size_t)s0 * HDIM + lane * 4);
        a0 += (float)v0[0]; a1 += (float)v0[1]; a2 += (float)v0[2]; a3 += (float)v0[3];
    }
    f16x4 r;
    r[0] = (f16)(a0 + b0); r[1] = (f16)(a1 + b1);
    r[2] = (f16)(a2 + b2); r[3] = (f16)(a3 + b3);
    *(f16x4*)(outp + (size_t)node * HDIM + lane * 4) = r;
}

__global__ __launch_bounds__(256) void fill1_k(float* __restrict__ p, int n)
{
    const int t = blockIdx.x * 256 + threadIdx.x;
    if (t < n) p[t] = 1.0f;
}

// ---------------------------------------------------------------------------
extern "C" void kernel_launch(void* const* d_in, const int* in_sizes, int n_in,
                              void* d_out, int out_size, void* d_ws, size_t ws_size,
                              hipStream_t stream)
{
    const int*   edge   = (const int*)d_in[1];
    const int*   src    = edge;
    const int*   dst    = edge + NEDGES;
    const float* esm    = (const float*)d_in[2];
    const float* lin0_W = (const float*)d_in[4];
    const float* lin0_b = (const float*)d_in[5];
    const float* wc_W1  = (const float*)d_in[6];
    const float* wc_b1  = (const float*)d_in[7];
    const float* wc_W2  = (const float*)d_in[8];
    const float* wc_b2  = (const float*)d_in[9];
    const float* wc_W3  = (const float*)d_in[10];
    const float* wc_b3  = (const float*)d_in[11];
    const float* sc_Wn  = (const float*)d_in[12];
    const float* sc_bn  = (const float*)d_in[13];
    const float* sc_Wr  = (const float*)d_in[14];
    float* out = (float*)d_out;

    const size_t NH = (size_t)NNODES * HDIM;
    f16* aggx  = (f16*)d_ws;
    f16* xg    = aggx + NH;
    f16* agg2  = xg + NH;
    f16* xh    = agg2 + NH;
    f16* xm    = xh + NH;
    f16* maskh = xm + NH;
    f16* esmh  = maskh + NH;              // [N][1280] f16 = 128 MB
    f16* wpack = esmh + (size_t)NNODES * FIN;
    f16* lin0t = wpack;                   // 327680
    f16* WH    = lin0t + 327680;          // 524288
    f16* W3t   = WH + 524288;             // 262144
    f16* WtC   = W3t + 262144;            // 524288
    int* iws    = (int*)(WtC + 524288);
    int* counts = iws;                    // degree table
    int* starts = iws + NNODES;
    int* cursor = iws + 2 * NNODES + 1;
    int* csr    = iws + 3 * NNODES + 2;
    int* bsums  = csr + NEDGES;           // [196]

    const dim3 blk(256);
    const int gemmGrid = (NNODES + 63) / 64;           // 782
    const int edgeGrid = (NEDGES + 255) / 256;
    const int waveGrid = (NNODES * 64) / 256;          // 12500
    const int scanGrid = (NNODES + 255) / 256;         // 196

    // ---- CSR build (hierarchical scan)
    hipMemsetAsync(counts, 0, NNODES * sizeof(int), stream);
    count_k<<<edgeGrid, blk, 0, stream>>>(dst, counts);
    scan1_k<<<scanGrid, blk, 0, stream>>>(counts, starts, bsums);
    scan2_k<<<1, blk, 0, stream>>>(bsums, scanGrid);
    scan3_k<<<scanGrid, blk, 0, stream>>>(bsums, starts);
    hipMemcpyAsync(cursor, starts, NNODES * sizeof(int),
                   hipMemcpyDeviceToDevice, stream);
    fillcsr_k<<<edgeGrid, blk, 0, stream>>>(src, dst, cursor, csr);

    // ---- packs + esm f16 convert
    pack_all_k<<<(1638400 + 255) / 256, blk, 0, stream>>>(
        lin0_W, wc_W2, wc_W1, wc_W3, sc_Wn, sc_Wr, wpack);
    tof16_k<<<2048, blk, 0, stream>>>(esm, esmh);

    // ---- lin0: xh = f16(esmh @ lin0t + b)
    lin0h_k<<<gemmGrid, blk, 0, stream>>>(esmh, lin0t, lin0_b, xh);

    for (int i = 0; i < NLAYERS; ++i) {
        const size_t bo = (size_t)i * HDIM;
        const f16* wh = WH + (size_t)i * 131072;
        const f16* w3 = W3t + (size_t)i * 65536;
        const f16* wc = WtC + (size_t)i * 131072;
        const f16* xmtab = (i == 0) ? xh : xm;   // layer 0: mask is None

        // aggx = segment_sum(xm[src], dst)
        gather_g_k<<<waveGrid, blk, 0, stream>>>(xmtab, csr, starts, aggx);
        // fused: h = relu([aggx|xm]@[W2;W1]+deg*b2+b1) in LDS;
        //        mask = sigmoid(h@W3+b3); xg = xh*mask
        hm_k<<<gemmGrid, blk, 0, stream>>>(
            aggx, xmtab, xh, counts, wh, w3,
            wc_b2 + bo, wc_b1 + bo, wc_b3 + bo, maskh, xg);
        // agg2 = segment_sum(xg[src], dst)
        gather_g_k<<<waveGrid, blk, 0, stream>>>(xg, csr, starts, agg2);
        // x' = relu([agg2|xh]@[Wn;Wr]+bn) -> out slice, xh (in-place), xm'
        cath2_k<<<gemmGrid, blk, 0, stream>>>(
            agg2, xh, maskh, wc, sc_bn + bo,
            out + (size_t)i * HDIM, LDOUT, xh, xm);
    }

    // node_mask: all true
    const size_t maskOff = (size_t)NNODES * LDOUT;
    fill1_k<<<(NNODES + 255) / 256, blk, 0, stream>>>(out + maskOff, NNODES);
}

// Round 17
// 1233.476 us; speedup vs baseline: 1.0949x; 1.0949x over previous
//
#include <hip/hip_runtime.h>

#define NNODES 50000
#define HDIM 256
#define NLAYERS 4
#define NEDGES 800000
#define FIN 1280
#define LDOUT 1024

typedef _Float16 f16;
typedef __attribute__((ext_vector_type(8))) _Float16 f16x8;
typedef __attribute__((ext_vector_type(4))) _Float16 f16x4;
typedef __attribute__((ext_vector_type(4))) float f32x4;

// ---------------------------------------------------------------------------
// MFMA layouts refcheck-validated R3-R15: A row=l&15, k=(l>>4)*8+j (+32kb);
// B col=l&15 (col-major Wt); C/D col=l&15, row=(l>>4)*4+reg.
// Frag-major LDS layout (R11-verified):
//   (row,col) -> (((col>>6)*8+((col>>5)&1)*4+(row>>4))*64
//                 + ((col>>3)&3)*16 + (row&15))*8 + (col&7)
// R14 lesson: keep LDS-staged A via registers (coalesced + block reuse).
// R16 lesson: gll16 depth-1 pipeline regressed vs depth-2 reg prefetch.
// ---------------------------------------------------------------------------

// ---------------------------------------------------------------------------
// Fused h + mask GEMM (hm_k)  [R13/R15-verified]:
// phase A: h = relu([aggx|xm]@[W2;W1] + deg*b2 + b1)  (K=512, LDS-staged),
//          epilogue -> frag-major LDS (no global h)
// phase B: mask = sigmoid(h@W3 + b3) (K=256, A from LDS, barrier-free)
// epilogue B: maskh = m; xg = xh*m
// ---------------------------------------------------------------------------
__global__ __launch_bounds__(256) void hm_k(
    const f16*  __restrict__ aggx,
    const f16*  __restrict__ xm,
    const f16*  __restrict__ xh,
    const int*  __restrict__ deg,
    const f16*  __restrict__ WH,      // [256][512] col-major
    const f16*  __restrict__ W3t,     // [256][256] col-major
    const float* __restrict__ b2,
    const float* __restrict__ b1,
    const float* __restrict__ b3,
    f16* __restrict__ maskh,
    f16* __restrict__ xg)
{
    __shared__ f16 lds[16384];        // 32 KB: phase A dbuf overlay + Hfr

    const int row0 = blockIdx.x * 64;
    const int tid = threadIdx.x;
    const int wv = tid >> 6;
    const int l = tid & 63;

    f32x4 acc[4][4] = {};

    const int sr = tid >> 2;
    const int sc0 = (tid & 3) * 16;
    const int grow = row0 + sr;
    const bool rok = grow < NNODES;
    const int lane_base0 =
        (((sc0 >> 5) * 4 + (sr >> 4)) * 64 + (sr & 15) + (((sc0 & 31) >> 3) * 16)) * 8;
    const int lane_base1 = lane_base0 + 128;

    const f16* bp[4];
    #pragma unroll
    for (int cf = 0; cf < 4; ++cf)
        bp[cf] = WH + (size_t)(wv * 64 + cf * 16 + (l & 15)) * 512 + ((l >> 4) * 8);

    struct SReg { f16x8 h0, h1; };
    SReg RA, RB;

    auto LOAD = [&](SReg& r, int kt) {
        if (!rok) return;
        const int k0 = kt * 64 + sc0;
        const f16* p = (k0 < HDIM) ? (aggx + (size_t)grow * HDIM + k0)
                                   : (xm + (size_t)grow * HDIM + (k0 - HDIM));
        r.h0 = *(const f16x8*)p;  r.h1 = *(const f16x8*)(p + 8);
    };

    auto COMMIT = [&](const SReg& r, int b) {
        f16x8 av0, av1;
        #pragma unroll
        for (int i = 0; i < 8; ++i) { av0[i] = (f16)0.f; av1[i] = (f16)0.f; }
        if (rok) { av0 = r.h0; av1 = r.h1; }
        *(f16x8*)(&lds[b * 4096 + lane_base0]) = av0;
        *(f16x8*)(&lds[b * 4096 + lane_base1]) = av1;
    };

    auto TILE = [&](int b, int kt) {
        f16x8 af[4][2];
        #pragma unroll
        for (int rf = 0; rf < 4; ++rf)
            #pragma unroll
            for (int kb = 0; kb < 2; ++kb)
                af[rf][kb] = *(const f16x8*)(&lds[b * 4096 + ((kb * 4 + rf) * 64 + l) * 8]);
        f16x8 bfr[4][2];
        #pragma unroll
        for (int cf = 0; cf < 4; ++cf) {
            bfr[cf][0] = *(const f16x8*)(bp[cf] + kt * 64);
            bfr[cf][1] = *(const f16x8*)(bp[cf] + kt * 64 + 32);
        }
        #pragma unroll
        for (int cf = 0; cf < 4; ++cf)
            #pragma unroll
            for (int rf = 0; rf < 4; ++rf)
                #pragma unroll
                for (int kb = 0; kb < 2; ++kb)
                    acc[rf][cf] = __builtin_amdgcn_mfma_f32_16x16x32_f16(
                        af[rf][kb], bfr[cf][kb], acc[rf][cf], 0, 0, 0);
    };

    LOAD(RA, 0);
    COMMIT(RA, 0);
    LOAD(RB, 1);
    #pragma unroll
    for (int kt2 = 0; kt2 < 8; kt2 += 2) {
        __syncthreads();
        TILE(0, kt2);
        COMMIT(RB, 1);
        if (kt2 + 2 < 8) LOAD(RA, kt2 + 2);
        __syncthreads();
        TILE(1, kt2 + 1);
        if (kt2 + 2 < 8) COMMIT(RA, 0);
        if (kt2 + 3 < 8) LOAD(RB, kt2 + 3);
    }
    __syncthreads();                  // all reads of Asm done -> reuse as Hfr

    // epilogue A: h -> frag-major LDS
    #pragma unroll
    for (int rf = 0; rf < 4; ++rf) {
        #pragma unroll
        for (int j = 0; j < 4; ++j) {
            const int rowl = rf * 16 + ((l >> 4) * 4) + j;
            const int row = row0 + rowl;
            const float dv = (row < NNODES) ? (float)deg[row] : 0.f;
            #pragma unroll
            for (int cf = 0; cf < 4; ++cf) {
                const int col = wv * 64 + cf * 16 + (l & 15);
                const float h = fmaxf(acc[rf][cf][j] + dv * b2[col] + b1[col], 0.f);
                const int idx =
                    (((col >> 6) * 8 + ((col >> 5) & 1) * 4 + (rowl >> 4)) * 64
                     + ((col >> 3) & 3) * 16 + (rowl & 15)) * 8 + (col & 7);
                lds[idx] = (f16)h;
            }
        }
    }
    __syncthreads();

    // ------------- phase B: mask GEMM (A = Hfr, K=256) -------------
    const f16* bp3[4];
    #pragma unroll
    for (int cf = 0; cf < 4; ++cf)
        bp3[cf] = W3t + (size_t)(wv * 64 + cf * 16 + (l & 15)) * 256 + ((l >> 4) * 8);

    f32x4 acc2[4][4] = {};
    f16x8 bC[4][2], bN[4][2];
    #pragma unroll
    for (int cf = 0; cf < 4; ++cf) {
        bC[cf][0] = *(const f16x8*)(bp3[cf]);
        bC[cf][1] = *(const f16x8*)(bp3[cf] + 32);
    }
    #pragma unroll
    for (int kt = 0; kt < 4; ++kt) {
        if (kt < 3) {
            #pragma unroll
            for (int cf = 0; cf < 4; ++cf) {
                bN[cf][0] = *(const f16x8*)(bp3[cf] + (kt + 1) * 64);
                bN[cf][1] = *(const f16x8*)(bp3[cf] + (kt + 1) * 64 + 32);
            }
        }
        f16x8 af[4][2];
        #pragma unroll
        for (int rf = 0; rf < 4; ++rf)
            #pragma unroll
            for (int kb = 0; kb < 2; ++kb)
                af[rf][kb] = *(const f16x8*)(&lds[((kt * 8 + kb * 4 + rf) * 64 + l) * 8]);
        #pragma unroll
        for (int cf = 0; cf < 4; ++cf)
            #pragma unroll
            for (int rf = 0; rf < 4; ++rf)
                #pragma unroll
                for (int kb = 0; kb < 2; ++kb)
                    acc2[rf][cf] = __builtin_amdgcn_mfma_f32_16x16x32_f16(
                        af[rf][kb], bC[cf][kb], acc2[rf][cf], 0, 0, 0);
        if (kt < 3) {
            #pragma unroll
            for (int cf = 0; cf < 4; ++cf) {
                bC[cf][0] = bN[cf][0];  bC[cf][1] = bN[cf][1];
            }
        }
    }

    // epilogue B: mask + xg
    #pragma unroll
    for (int rf = 0; rf < 4; ++rf) {
        #pragma unroll
        for (int j = 0; j < 4; ++j) {
            const int row = row0 + rf * 16 + ((l >> 4) * 4) + j;
            if (row >= NNODES) continue;
            #pragma unroll
            for (int cf = 0; cf < 4; ++cf) {
                const int col = wv * 64 + cf * 16 + (l & 15);
                const float m = 1.f / (1.f + expf(-(acc2[rf][cf][j] + b3[col])));
                maskh[(size_t)row * HDIM + col] = (f16)m;
                xg[(size_t)row * HDIM + col] =
                    (f16)((float)xh[(size_t)row * HDIM + col] * m);
            }
        }
    }
}

// ---------------------------------------------------------------------------
// CATH2 GEMM (R12/R15-verified): x' = relu([agg2|xh]@[Wn;Wr] + bn)
// -> out (f32 ld 1024), xh (f16, in-place safe), xm' = x'*mask
// ---------------------------------------------------------------------------
__global__ __launch_bounds__(256) void cath2_k(
    const f16*  __restrict__ A3,      // agg2
    const f16*  __restrict__ A4,      // xh (k>=256)
    const f16*  __restrict__ Mh,      // maskh
    const f16*  __restrict__ Wt,      // [256][512] col-major
    const float* __restrict__ bias,
    float* __restrict__ Cf, int ldc,
    f16*  __restrict__ Ch,            // xh (in-place)
    f16*  __restrict__ Ch3)           // xm'
{
    constexpr int KTILES = 8;
    constexpr int K = 512;
    __shared__ f16 Asm[2][4096];

    const int row0 = blockIdx.x * 64;
    const int tid = threadIdx.x;
    const int wv = tid >> 6;
    const int l = tid & 63;

    f32x4 acc[4][4] = {};

    const int sr = tid >> 2;
    const int sc0 = (tid & 3) * 16;
    const int grow = row0 + sr;
    const bool rok = grow < NNODES;
    const int lane_base0 =
        (((sc0 >> 5) * 4 + (sr >> 4)) * 64 + (sr & 15) + (((sc0 & 31) >> 3) * 16)) * 8;
    const int lane_base1 = lane_base0 + 128;

    const f16* bp[4];
    #pragma unroll
    for (int cf = 0; cf < 4; ++cf)
        bp[cf] = Wt + (size_t)(wv * 64 + cf * 16 + (l & 15)) * K + ((l >> 4) * 8);

    struct SReg { f16x8 h0, h1; };
    SReg RA, RB;

    auto LOAD = [&](SReg& r, int kt) {
        if (!rok) return;
        const int k0 = kt * 64 + sc0;
        const f16* p = (k0 < HDIM) ? (A3 + (size_t)grow * HDIM + k0)
                                   : (A4 + (size_t)grow * HDIM + (k0 - HDIM));
        r.h0 = *(const f16x8*)p;  r.h1 = *(const f16x8*)(p + 8);
    };

    auto COMMIT = [&](const SReg& r, int b) {
        f16x8 av0, av1;
        #pragma unroll
        for (int i = 0; i < 8; ++i) { av0[i] = (f16)0.f; av1[i] = (f16)0.f; }
        if (rok) { av0 = r.h0; av1 = r.h1; }
        *(f16x8*)(&Asm[b][lane_base0]) = av0;
        *(f16x8*)(&Asm[b][lane_base1]) = av1;
    };

    auto TILE = [&](int b, int kt) {
        f16x8 af[4][2];
        #pragma unroll
        for (int rf = 0; rf < 4; ++rf)
            #pragma unroll
            for (int kb = 0; kb < 2; ++kb)
                af[rf][kb] = *(const f16x8*)(&Asm[b][((kb * 4 + rf) * 64 + l) * 8]);
        f16x8 bfr[4][2];
        #pragma unroll
        for (int cf = 0; cf < 4; ++cf) {
            bfr[cf][0] = *(const f16x8*)(bp[cf] + kt * 64);
            bfr[cf][1] = *(const f16x8*)(bp[cf] + kt * 64 + 32);
        }
        #pragma unroll
        for (int cf = 0; cf < 4; ++cf)
            #pragma unroll
            for (int rf = 0; rf < 4; ++rf)
                #pragma unroll
                for (int kb = 0; kb < 2; ++kb)
                    acc[rf][cf] = __builtin_amdgcn_mfma_f32_16x16x32_f16(
                        af[rf][kb], bfr[cf][kb], acc[rf][cf], 0, 0, 0);
    };

    LOAD(RA, 0);
    COMMIT(RA, 0);
    LOAD(RB, 1);
    #pragma unroll
    for (int kt2 = 0; kt2 < KTILES; kt2 += 2) {
        __syncthreads();
        TILE(0, kt2);
        COMMIT(RB, 1);
        if (kt2 + 2 < KTILES) LOAD(RA, kt2 + 2);
        __syncthreads();
        TILE(1, kt2 + 1);
        if (kt2 + 2 < KTILES) COMMIT(RA, 0);
        if (kt2 + 3 < KTILES) LOAD(RB, kt2 + 3);
    }

    #pragma unroll
    for (int rf = 0; rf < 4; ++rf) {
        #pragma unroll
        for (int j = 0; j < 4; ++j) {
            const int row = row0 + rf * 16 + ((l >> 4) * 4) + j;
            if (row >= NNODES) continue;
            #pragma unroll
            for (int cf = 0; cf < 4; ++cf) {
                const int col = wv * 64 + cf * 16 + (l & 15);
                const float r = fmaxf(acc[rf][cf][j] + bias[col], 0.f);
                Cf[(size_t)row * ldc + col] = r;
                Ch[(size_t)row * HDIM + col] = (f16)r;
                Ch3[(size_t)row * HDIM + col] =
                    (f16)(r * (float)Mh[(size_t)row * HDIM + col]);
            }
        }
    }
}

// ---------------------------------------------------------------------------
// lin0 GEMM (R12/R15): K-split x4, f16 partials.
// ---------------------------------------------------------------------------
template<int KTILES>
__global__ __launch_bounds__(256) void lin0_k(
    const float* __restrict__ A1, int lda1,
    const f16*  __restrict__ WtBase,
    f16* __restrict__ parts)
{
    constexpr int K = KTILES * 64;     // 320
    __shared__ f16 Asm[2][4096];

    const int row0 = blockIdx.x * 64;
    const int by = blockIdx.y;
    const int tid = threadIdx.x;
    const int wv = tid >> 6;
    const int l = tid & 63;

    f32x4 acc[4][4] = {};

    const int sr = tid >> 2;
    const int sc0 = (tid & 3) * 16;
    const int grow = row0 + sr;
    const bool rok = grow < NNODES;
    const int kg = by * K;
    const int lane_base0 =
        (((sc0 >> 5) * 4 + (sr >> 4)) * 64 + (sr & 15) + (((sc0 & 31) >> 3) * 16)) * 8;
    const int lane_base1 = lane_base0 + 128;

    const f16* Wsel = WtBase + (size_t)by * 256 * K;
    const f16* bp[4];
    #pragma unroll
    for (int cf = 0; cf < 4; ++cf)
        bp[cf] = Wsel + (size_t)(wv * 64 + cf * 16 + (l & 15)) * K + ((l >> 4) * 8);

    struct SReg { float4 f0, f1, f2, f3; };
    SReg RA, RB;

    auto LOAD = [&](SReg& r, int kt) {
        if (!rok) return;
        const float* p = A1 + (size_t)grow * lda1 + kg + kt * 64 + sc0;
        r.f0 = *(const float4*)(p + 0);  r.f1 = *(const float4*)(p + 4);
        r.f2 = *(const float4*)(p + 8);  r.f3 = *(const float4*)(p + 12);
    };

    auto COMMIT = [&](const SReg& r, int b) {
        f16x8 av0, av1;
        #pragma unroll
        for (int i = 0; i < 8; ++i) { av0[i] = (f16)0.f; av1[i] = (f16)0.f; }
        if (rok) {
            av0[0]=(f16)r.f0.x; av0[1]=(f16)r.f0.y; av0[2]=(f16)r.f0.z; av0[3]=(f16)r.f0.w;
            av0[4]=(f16)r.f1.x; av0[5]=(f16)r.f1.y; av0[6]=(f16)r.f1.z; av0[7]=(f16)r.f1.w;
            av1[0]=(f16)r.f2.x; av1[1]=(f16)r.f2.y; av1[2]=(f16)r.f2.z; av1[3]=(f16)r.f2.w;
            av1[4]=(f16)r.f3.x; av1[5]=(f16)r.f3.y; av1[6]=(f16)r.f3.z; av1[7]=(f16)r.f3.w;
        }
        *(f16x8*)(&Asm[b][lane_base0]) = av0;
        *(f16x8*)(&Asm[b][lane_base1]) = av1;
    };

    auto TILE = [&](int b, int kt) {
        f16x8 af[4][2];
        #pragma unroll
        for (int rf = 0; rf < 4; ++rf)
            #pragma unroll
            for (int kb = 0; kb < 2; ++kb)
                af[rf][kb] = *(const f16x8*)(&Asm[b][((kb * 4 + rf) * 64 + l) * 8]);
        f16x8 bfr[4][2];
        #pragma unroll
        for (int cf = 0; cf < 4; ++cf) {
            bfr[cf][0] = *(const f16x8*)(bp[cf] + kt * 64);
            bfr[cf][1] = *(const f16x8*)(bp[cf] + kt * 64 + 32);
        }
        #pragma unroll
        for (int cf = 0; cf < 4; ++cf)
            #pragma unroll
            for (int rf = 0; rf < 4; ++rf)
                #pragma unroll
                for (int kb = 0; kb < 2; ++kb)
                    acc[rf][cf] = __builtin_amdgcn_mfma_f32_16x16x32_f16(
                        af[rf][kb], bfr[cf][kb], acc[rf][cf], 0, 0, 0);
    };

    LOAD(RA, 0);
    COMMIT(RA, 0);
    if (KTILES > 1) LOAD(RB, 1);
    #pragma unroll
    for (int kt2 = 0; kt2 < KTILES; kt2 += 2) {
        __syncthreads();
        TILE(0, kt2);
        if (kt2 + 1 < KTILES) COMMIT(RB, 1);
        if (kt2 + 2 < KTILES) LOAD(RA, kt2 + 2);
        if (kt2 + 1 < KTILES) {
            __syncthreads();
            TILE(1, kt2 + 1);
            if (kt2 + 2 < KTILES) COMMIT(RA, 0);
            if (kt2 + 3 < KTILES) LOAD(RB, kt2 + 3);
        }
    }

    f16* Ph = parts + (size_t)by * NNODES * HDIM;
    #pragma unroll
    for (int rf = 0; rf < 4; ++rf) {
        #pragma unroll
        for (int j = 0; j < 4; ++j) {
            const int row = row0 + rf * 16 + ((l >> 4) * 4) + j;
            if (row >= NNODES) continue;
            #pragma unroll
            for (int cf = 0; cf < 4; ++cf) {
                const int col = wv * 64 + cf * 16 + (l & 15);
                Ph[(size_t)row * HDIM + col] = (f16)acc[rf][cf][j];
            }
        }
    }
}

__global__ __launch_bounds__(256) void combine4_k(
    const f16* __restrict__ parts, const float* __restrict__ b,
    f16* __restrict__ xh)
{
    const int t = blockIdx.x * 256 + threadIdx.x;
    const int row = t >> 6;
    const int c = (t & 63) * 4;
    if (row >= NNODES) return;
    const size_t NH = (size_t)NNODES * HDIM;
    const size_t off = (size_t)row * HDIM + c;
    f16x4 p0 = *(const f16x4*)(parts + off);
    f16x4 p1 = *(const f16x4*)(parts + NH + off);
    f16x4 p2 = *(const f16x4*)(parts + 2 * NH + off);
    f16x4 p3 = *(const f16x4*)(parts + 3 * NH + off);
    const float4 bb = *(const float4*)(b + c);
    f16x4 r;
    r[0] = (f16)((float)p0[0] + (float)p1[0] + (float)p2[0] + (float)p3[0] + bb.x);
    r[1] = (f16)((float)p0[1] + (float)p1[1] + (float)p2[1] + (float)p3[1] + bb.y);
    r[2] = (f16)((float)p0[2] + (float)p1[2] + (float)p2[2] + (float)p3[2] + bb.z);
    r[3] = (f16)((float)p0[3] + (float)p1[3] + (float)p2[3] + (float)p3[3] + bb.w);
    *(f16x4*)(xh + off) = r;
}

// ---------------------------------------------------------------------------
// ONE fused weight-pack kernel (R12 layout, verified).
// ---------------------------------------------------------------------------
__global__ __launch_bounds__(256) void pack_all_k(
    const float* __restrict__ lin0_W,
    const float* __restrict__ W2, const float* __restrict__ W1,
    const float* __restrict__ W3,
    const float* __restrict__ Wn, const float* __restrict__ Wr,
    f16* __restrict__ dst)
{
    int idx = blockIdx.x * 256 + threadIdx.x;
    const int total = 327680 + 524288 + 262144 + 524288;
    if (idx >= total) return;
    f16* d = dst + idx;
    if (idx < 327680) {                       // lin0 K-quarter slices
        const int q = idx / 81920;
        int r = idx % 81920;
        const int col = r / 320, k = r % 320;
        *d = (f16)lin0_W[(size_t)(k + q * 320) * 256 + col];
        return;
    }
    idx -= 327680;
    if (idx < 524288) {                       // WH = [W2;W1]
        const int i = idx / 131072;
        int r = idx % 131072;
        const int col = r / 512, k = r % 512;
        *d = (f16)(k < 256 ? W2[(size_t)i * 65536 + k * 256 + col]
                           : W1[(size_t)i * 65536 + (k - 256) * 256 + col]);
        return;
    }
    idx -= 524288;
    if (idx < 262144) {                       // W3t
        const int i = idx / 65536;
        int r = idx % 65536;
        const int col = r / 256, k = r % 256;
        *d = (f16)W3[(size_t)i * 65536 + k * 256 + col];
        return;
    }
    idx -= 262144;                            // WtC = [Wn;Wr]
    const int i = idx / 131072; int r = idx % 131072;
    const int col = r / 512, k = r % 512;
    *d = (f16)(k < 256 ? Wn[(size_t)i * 65536 + k * 256 + col]
                       : Wr[(size_t)i * 65536 + (k - 256) * 256 + col]);
}

// ---------------------------------------------------------------------------
// CSR build: histogram -> 3-phase hierarchical scan (R15-verified) -> fill
// scan3 now also writes cursor (removes the D2D memcpy node).
// ---------------------------------------------------------------------------
__global__ __launch_bounds__(256) void count_k(
    const int* __restrict__ dstIdx, int* __restrict__ counts)
{
    const int e = blockIdx.x * 256 + threadIdx.x;
    if (e < NEDGES) atomicAdd(&counts[dstIdx[e]], 1);
}

__global__ __launch_bounds__(256) void scan1_k(
    const int* __restrict__ counts, int* __restrict__ starts,
    int* __restrict__ bsums)
{
    __shared__ int sm[256];
    const int i = blockIdx.x * 256 + threadIdx.x;
    const int v = (i < NNODES) ? counts[i] : 0;
    sm[threadIdx.x] = v;
    __syncthreads();
    #pragma unroll
    for (int ofs = 1; ofs < 256; ofs <<= 1) {
        const int t = (threadIdx.x >= ofs) ? sm[threadIdx.x - ofs] : 0;
        __syncthreads();
        sm[threadIdx.x] += t;
        __syncthreads();
    }
    if (i < NNODES) starts[i] = sm[threadIdx.x] - v;
    if (threadIdx.x == 255) bsums[blockIdx.x] = sm[255];
}

__global__ __launch_bounds__(256) void scan2_k(int* __restrict__ bsums, int nb)
{
    __shared__ int sm[256];
    const int v = (threadIdx.x < nb) ? bsums[threadIdx.x] : 0;
    sm[threadIdx.x] = v;
    __syncthreads();
    #pragma unroll
    for (int ofs = 1; ofs < 256; ofs <<= 1) {
        const int t = (threadIdx.x >= ofs) ? sm[threadIdx.x - ofs] : 0;
        __syncthreads();
        sm[threadIdx.x] += t;
        __syncthreads();
    }
    if (threadIdx.x < nb) bsums[threadIdx.x] = sm[threadIdx.x] - v;
}

__global__ __launch_bounds__(256) void scan3_k(
    const int* __restrict__ bsums, int* __restrict__ starts,
    int* __restrict__ cursor)
{
    const int i = blockIdx.x * 256 + threadIdx.x;
    if (i < NNODES) {
        const int v = starts[i] + bsums[blockIdx.x];
        starts[i] = v;
        cursor[i] = v;
    }
    if (i == 0) starts[NNODES] = NEDGES;
}

__global__ __launch_bounds__(256) void fillcsr_k(
    const int* __restrict__ srcIdx, const int* __restrict__ dstIdx,
    int* __restrict__ cursor, int* __restrict__ csr)
{
    const int e = blockIdx.x * 256 + threadIdx.x;
    if (e >= NEDGES) return;
    const int d = dstIdx[e];
    const int p = atomicAdd(&cursor[d], 1);
    csr[p] = srcIdx[e];
}

// ---------------------------------------------------------------------------
// gather-sum (R10-verified): one wave per node, f16 rows, f32 accum, unroll-4
// ---------------------------------------------------------------------------
__global__ __launch_bounds__(256) void gather_g_k(
    const f16* __restrict__ rows, const int* __restrict__ csr,
    const int* __restrict__ starts, f16* __restrict__ outp)
{
    const int node = (blockIdx.x * 256 + threadIdx.x) >> 6;
    const int lane = threadIdx.x & 63;
    if (node >= NNODES) return;
    const int e0 = starts[node], e1 = starts[node + 1];
    float a0=0,a1=0,a2=0,a3=0, b0=0,b1=0,b2=0,b3=0;
    int e = e0;
    for (; e + 3 < e1; e += 4) {
        const int s0=csr[e], s1=csr[e+1], s2=csr[e+2], s3=csr[e+3];
        f16x4 v0 = *(const f16x4*)(rows + (size_t)s0 * HDIM + lane * 4);
        f16x4 v1 = *(const f16x4*)(rows + (size_t)s1 * HDIM + lane * 4);
        f16x4 v2 = *(const f16x4*)(rows + (size_t)s2 * HDIM + lane * 4);
        f16x4 v3 = *(const f16x4*)(rows + (size_t)s3 * HDIM + lane * 4);
        a0 += (float)v0[0] + (float)v2[0]; a1 += (float)v0[1] + (float)v2[1];
        a2 += (float)v0[2] + (float)v2[2]; a3 += (float)v0[3] + (float)v2[3];
        b0 += (float)v1[0] + (float)v3[0]; b1 += (float)v1[1] + (float)v3[1];
        b2 += (float)v1[2] + (float)v3[2]; b3 += (float)v1[3] + (float)v3[3];
    }
    for (; e < e1; ++e) {
        const int s0 = csr[e];
        f16x4 v0 = *(const f16x4*)(rows + (size_t)s0 * HDIM + lane * 4);
        a0 += (float)v0[0]; a1 += (float)v0[1]; a2 += (float)v0[2]; a3 += (float)v0[3];
    }
    f16x4 r;
    r[0] = (f16)(a0 + b0); r[1] = (f16)(a1 + b1);
    r[2] = (f16)(a2 + b2); r[3] = (f16)(a3 + b3);
    *(f16x4*)(outp + (size_t)node * HDIM + lane * 4) = r;
}

__global__ __launch_bounds__(256) void fill1_k(float* __restrict__ p, int n)
{
    const int t = blockIdx.x * 256 + threadIdx.x;
    if (t < n) p[t] = 1.0f;
}

// ---------------------------------------------------------------------------
extern "C" void kernel_launch(void* const* d_in, const int* in_sizes, int n_in,
                              void* d_out, int out_size, void* d_ws, size_t ws_size,
                              hipStream_t stream)
{
    const int*   edge   = (const int*)d_in[1];
    const int*   src    = edge;
    const int*   dst    = edge + NEDGES;
    const float* esm    = (const float*)d_in[2];
    const float* lin0_W = (const float*)d_in[4];
    const float* lin0_b = (const float*)d_in[5];
    const float* wc_W1  = (const float*)d_in[6];
    const float* wc_b1  = (const float*)d_in[7];
    const float* wc_W2  = (const float*)d_in[8];
    const float* wc_b2  = (const float*)d_in[9];
    const float* wc_W3  = (const float*)d_in[10];
    const float* wc_b3  = (const float*)d_in[11];
    const float* sc_Wn  = (const float*)d_in[12];
    const float* sc_bn  = (const float*)d_in[13];
    const float* sc_Wr  = (const float*)d_in[14];
    float* out = (float*)d_out;

    const size_t NH = (size_t)NNODES * HDIM;
    f16* parts = (f16*)d_ws;              // 4 x NH lin0 partials; reused:
    f16* aggx  = parts;                   //   p0 -> aggx
    f16* xg    = parts + NH;              //   p1 -> xg
    f16* agg2  = parts + 2 * NH;          //   p2 -> agg2
    f16* xh    = parts + 4 * NH;          // persistent x
    f16* xm    = xh + NH;                 // persistent x*mask
    f16* maskh = xm + NH;                 // persistent mask
    f16* wpack = maskh + NH;
    f16* lin0t = wpack;                   // 327680
    f16* WH    = lin0t + 327680;          // 524288
    f16* W3t   = WH + 524288;             // 262144
    f16* WtC   = W3t + 262144;            // 524288
    int* iws    = (int*)(WtC + 524288);
    int* counts = iws;                    // degree table
    int* starts = iws + NNODES;
    int* cursor = iws + 2 * NNODES + 1;
    int* csr    = iws + 3 * NNODES + 2;
    int* bsums  = csr + NEDGES;           // [196]

    const dim3 blk(256);
    const int gemmGrid = (NNODES + 63) / 64;           // 782
    const int edgeGrid = (NEDGES + 255) / 256;
    const int waveGrid = (NNODES * 64) / 256;          // 12500
    const int scanGrid = (NNODES + 255) / 256;         // 196

    // ---- CSR build (hierarchical scan; cursor written in scan3)
    hipMemsetAsync(counts, 0, NNODES * sizeof(int), stream);
    count_k<<<edgeGrid, blk, 0, stream>>>(dst, counts);
    scan1_k<<<scanGrid, blk, 0, stream>>>(counts, starts, bsums);
    scan2_k<<<1, blk, 0, stream>>>(bsums, scanGrid);
    scan3_k<<<scanGrid, blk, 0, stream>>>(bsums, starts, cursor);
    fillcsr_k<<<edgeGrid, blk, 0, stream>>>(src, dst, cursor, csr);

    // ---- all weight packs in ONE dispatch
    pack_all_k<<<(1638400 + 255) / 256, blk, 0, stream>>>(
        lin0_W, wc_W2, wc_W1, wc_W3, sc_Wn, sc_Wr, wpack);

    // ---- lin0 K-split x4 -> f16 partials -> combine into xh
    lin0_k<5><<<dim3(gemmGrid, 4), blk, 0, stream>>>(esm, FIN, lin0t, parts);
    combine4_k<<<waveGrid, blk, 0, stream>>>(parts, lin0_b, xh);

    for (int i = 0; i < NLAYERS; ++i) {
        const size_t bo = (size_t)i * HDIM;
        const f16* wh = WH + (size_t)i * 131072;
        const f16* w3 = W3t + (size_t)i * 65536;
        const f16* wc = WtC + (size_t)i * 131072;
        const f16* xmtab = (i == 0) ? xh : xm;   // layer 0: mask is None

        // aggx = segment_sum(xm[src], dst)
        gather_g_k<<<waveGrid, blk, 0, stream>>>(xmtab, csr, starts, aggx);
        // fused: h = relu([aggx|xm]@[W2;W1]+deg*b2+b1) in LDS;
        //        mask = sigmoid(h@W3+b3); xg = xh*mask
        hm_k<<<gemmGrid, blk, 0, stream>>>(
            aggx, xmtab, xh, counts, wh, w3,
            wc_b2 + bo, wc_b1 + bo, wc_b3 + bo, maskh, xg);
        // agg2 = segment_sum(xg[src], dst)
        gather_g_k<<<waveGrid, blk, 0, stream>>>(xg, csr, starts, agg2);
        // x' = relu([agg2|xh]@[Wn;Wr]+bn) -> out slice, xh (in-place), xm'
        cath2_k<<<gemmGrid, blk, 0, stream>>>(
            agg2, xh, maskh, wc, sc_bn + bo,
            out + (size_t)i * HDIM, LDOUT, xh, xm);
    }

    // node_mask: all true
    const size_t maskOff = (size_t)NNODES * LDOUT;
    fill1_k<<<(NNODES + 255) / 256, blk, 0, stream>>>(out + maskOff, NNODES);
}